// Round 2
// baseline (3466.226 us; speedup 1.0000x reference)
//
#include <hip/hip_runtime.h>
#include <hip/hip_cooperative_groups.h>
#include <hip/hip_bf16.h>
#include <math.h>

namespace cg = cooperative_groups;

#define T_STEPS 100
#define B 256
#define Q 2048
#define H 1024
#define NIN 4096

typedef __attribute__((ext_vector_type(8))) short bf16x8;
typedef __attribute__((ext_vector_type(4))) short bf16x4;
typedef __attribute__((ext_vector_type(4))) float f32x4;

#define WM_BYTES (64 * 2048)          /* 64 rows x 1024 bf16, swizzled      */
#define HLDS_OFF WM_BYTES             /* 16 students x 512 bf16 (one K half) */
#define HLDS_BYTES (16 * 1024)
#define HOUT_OFF HLDS_OFF             /* reused after MFMA loop             */
#define LOGIT_OFF (HLDS_OFF + 2048)   /* 4 waves x 16 f32                   */
#define SMEM_BYTES (WM_BYTES + HLDS_BYTES) /* 147456 */

__device__ inline unsigned short f2bf(float f) {
    union { float f; unsigned int u; } c; c.f = f;
    unsigned int u = c.u + 0x7fffu + ((c.u >> 16) & 1u);
    return (unsigned short)(u >> 16);
}

__global__ __launch_bounds__(256, 1) void rnn_persistent(
    const int* __restrict__ x_idx, const int* __restrict__ y_idx,
    const float* __restrict__ truth,
    const float* __restrict__ Wm, const float* __restrict__ bm,
    const float* __restrict__ Wx, const float* __restrict__ bx_,
    const float* __restrict__ Wy, const float* __restrict__ by,
    const float* __restrict__ b_start,
    __hip_bfloat16* __restrict__ h0buf, __hip_bfloat16* __restrict__ h1buf,
    float* __restrict__ logits, float* __restrict__ out)
{
    extern __shared__ char lds[];
    cg::grid_group grid = cg::this_grid();

    const int tid = threadIdx.x;
    const int bid = blockIdx.x;
    const int rg = bid & 15;          /* row group: rows [rg*64, +64)      */
    const int sg = bid >> 4;          /* student group: [sg*16, +16)       */
    const int sbase = sg * 16;
    const int w  = tid >> 6;          /* wave 0..3 -> rows w*16..+15       */
    const int l  = tid & 63;
    const int lr = l & 15;            /* A-row / B-col lane index          */
    const int g  = l >> 4;            /* k-group / row-quad index          */

    /* ---- one-time setup ---- */
    /* Wm rows [rg*64, +64) -> LDS bf16, 16B-slot XOR-swizzled by row&7 */
    for (int it = 0; it < 64; ++it) {
        int idx4 = it * 256 + tid;
        int row  = idx4 >> 8;                 /* 0..63  */
        int kq   = (idx4 & 255) << 2;         /* 0..1020 step 4 */
        float4 v = *reinterpret_cast<const float4*>(&Wm[(size_t)(rg * 64 + row) * H + kq]);
        bf16x4 b4;
        b4[0] = (short)f2bf(v.x); b4[1] = (short)f2bf(v.y);
        b4[2] = (short)f2bf(v.z); b4[3] = (short)f2bf(v.w);
        int byte = row * 2048 + (((kq >> 3) ^ (row & 7)) << 4) + ((kq & 7) << 1);
        *reinterpret_cast<bf16x4*>(&lds[byte]) = b4;
    }
    /* h0 = b_start broadcast (zeros @ W_start.T == 0) */
    for (int idx = tid; idx < 16 * 64; idx += 256) {
        int s = idx >> 6, c = idx & 63;
        float bs = b_start[rg * 64 + c];
        h0buf[(size_t)(sbase + s) * H + rg * 64 + c] = __hip_bfloat16(bs);
    }
    if (bid < T_STEPS) logits[bid * B + tid] = 0.f;

    /* per-lane row-invariant bias: bm + bx for my 4 output rows */
    float bias_r[4];
    #pragma unroll
    for (int r = 0; r < 4; ++r) {
        int gi = rg * 64 + w * 16 + g * 4 + r;
        bias_r[r] = bm[gi] + bx_[gi];
    }

    grid.sync();

    /* ---- recurrence ---- */
    for (int t = 0; t < T_STEPS; ++t) {
        const __hip_bfloat16* hc = (t & 1) ? h1buf : h0buf;
        __hip_bfloat16*       hn = (t & 1) ? h0buf : h1buf;

        /* early per-lane gathers (consumed after MFMA loop -> latency hidden) */
        int xc = x_idx[t * B + sbase + lr];
        int yc = y_idx[t * B + sbase + lr];
        float wx_r[4], wy_r[4];
        #pragma unroll
        for (int r = 0; r < 4; ++r) {
            int gi = rg * 64 + w * 16 + g * 4 + r;
            wx_r[r] = Wx[(size_t)gi * NIN + xc];
            wy_r[r] = Wy[(size_t)yc * H + gi];
        }

        f32x4 acc = {0.f, 0.f, 0.f, 0.f};
        const int arow = w * 16 + lr;

        #pragma unroll
        for (int half = 0; half < 2; ++half) {
            const int kbase = half * 512;
            /* stage h slice half: 16 students x 512 bf16, swizzled */
            #pragma unroll
            for (int it = 0; it < 4; ++it) {
                int q = it * 256 + tid;       /* 16B-chunk id, 0..1023 */
                int srow = q >> 6, sl = q & 63;
                bf16x8 v = *reinterpret_cast<const bf16x8*>(
                    &hc[(size_t)(sbase + srow) * H + kbase + sl * 8]);
                *reinterpret_cast<bf16x8*>(
                    &lds[HLDS_OFF + srow * 1024 + ((sl ^ (srow & 7)) << 4)]) = v;
            }
            __syncthreads();
            #pragma unroll
            for (int kk = 0; kk < 16; ++kk) {
                int aslot = (kbase >> 3) + kk * 4 + g;
                bf16x8 a = *reinterpret_cast<const bf16x8*>(
                    &lds[arow * 2048 + ((aslot ^ (arow & 7)) << 4)]);
                int bslot = kk * 4 + g;
                bf16x8 bb = *reinterpret_cast<const bf16x8*>(
                    &lds[HLDS_OFF + lr * 1024 + ((bslot ^ (lr & 7)) << 4)]);
                acc = __builtin_amdgcn_mfma_f32_16x16x32_bf16(a, bb, acc, 0, 0, 0);
            }
            __syncthreads();  /* h_lds half consumed before overwrite */
        }

        /* epilogue: bias + x-projection, tanh */
        float hv[4];
        #pragma unroll
        for (int r = 0; r < 4; ++r)
            hv[r] = tanhf(acc[r] + bias_r[r] + wx_r[r]);

        /* h_out tile (16 students x 64 rows bf16) -> LDS, swizzled by student */
        {
            int row0  = w * 16 + g * 4;
            int chunk = row0 >> 3;
            bf16x4 b4;
            b4[0] = (short)f2bf(hv[0]); b4[1] = (short)f2bf(hv[1]);
            b4[2] = (short)f2bf(hv[2]); b4[3] = (short)f2bf(hv[3]);
            int byte = HOUT_OFF + lr * 128 + ((chunk ^ (lr & 7)) << 4) + ((row0 & 7) << 1);
            *reinterpret_cast<bf16x4*>(&lds[byte]) = b4;
        }
        /* logit partial: this wave's 16 rows for student lr (f32 h, pre-round) */
        {
            float p = hv[0] * wy_r[0] + hv[1] * wy_r[1] + hv[2] * wy_r[2] + hv[3] * wy_r[3];
            p += __shfl_down(p, 32);
            p += __shfl_down(p, 16);
            if (l < 16)
                *reinterpret_cast<float*>(&lds[LOGIT_OFF + (w * 16 + l) * 4]) = p;
        }
        __syncthreads();
        /* coalesced h_next write-out: 16 students x 128B */
        if (tid < 128) {
            int s = tid >> 3, ch = tid & 7;
            bf16x8 v = *reinterpret_cast<const bf16x8*>(
                &lds[HOUT_OFF + s * 128 + ((ch ^ (s & 7)) << 4)]);
            *reinterpret_cast<bf16x8*>(&hn[(size_t)(sbase + s) * H + rg * 64 + ch * 8]) = v;
        }
        if (tid < 16) {
            const float* lg = reinterpret_cast<const float*>(&lds[LOGIT_OFF]);
            float ps = lg[tid] + lg[16 + tid] + lg[32 + tid] + lg[48 + tid];
            atomicAdd(&logits[t * B + sbase + tid], ps);
        }
        grid.sync();
    }

    /* ---- final: pred & loss ---- */
    if (bid < T_STEPS) {
        int idx = bid * B + tid;
        int yc = y_idx[idx];
        float lg = logits[idx] + by[yc];
        float pred = 1.f / (1.f + expf(-lg));
        float tv = truth[idx];
        float e = log1pf(expf(-fabsf(lg)));
        float ls_pos = fminf(lg, 0.f) - e;
        float ls_neg = fminf(-lg, 0.f) - e;
        out[idx] = pred;
        out[T_STEPS * B + idx] = -(tv * ls_pos + (1.f - tv) * ls_neg);
    }
}

extern "C" void kernel_launch(void* const* d_in, const int* in_sizes, int n_in,
                              void* d_out, int out_size, void* d_ws, size_t ws_size,
                              hipStream_t stream) {
    const int*   x_idx   = (const int*)d_in[0];
    const int*   y_idx   = (const int*)d_in[1];
    const float* truth   = (const float*)d_in[2];
    const float* Wm      = (const float*)d_in[3];
    const float* bm      = (const float*)d_in[4];
    const float* Wx      = (const float*)d_in[5];
    const float* bx_     = (const float*)d_in[6];
    const float* Wy      = (const float*)d_in[7];
    const float* by      = (const float*)d_in[8];
    /* d_in[9] = W_start: dead (multiplied by zeros) */
    const float* b_start = (const float*)d_in[10];
    float* out = (float*)d_out;

    __hip_bfloat16* h0buf  = (__hip_bfloat16*)d_ws;                       /* 512 KB */
    __hip_bfloat16* h1buf  = (__hip_bfloat16*)((char*)d_ws + 524288);     /* 512 KB */
    float*          logits = (float*)((char*)d_ws + 1048576);             /* 100 KB */

    static int attr_set = 0;
    (void)attr_set;
    hipFuncSetAttribute(reinterpret_cast<const void*>(rnn_persistent),
                        hipFuncAttributeMaxDynamicSharedMemorySize, SMEM_BYTES);

    void* args[] = {
        (void*)&x_idx, (void*)&y_idx, (void*)&truth,
        (void*)&Wm, (void*)&bm, (void*)&Wx, (void*)&bx_,
        (void*)&Wy, (void*)&by, (void*)&b_start,
        (void*)&h0buf, (void*)&h1buf, (void*)&logits, (void*)&out
    };
    hipLaunchCooperativeKernel(reinterpret_cast<void*>(rnn_persistent),
                               dim3(256), dim3(256), args, SMEM_BYTES, stream);
}

// Round 4
// 492.722 us; speedup vs baseline: 7.0348x; 7.0348x over previous
//
#include <hip/hip_runtime.h>
#include <hip/hip_bf16.h>
#include <math.h>

#define T_STEPS 100
#define B 256
#define Q 2048
#define H 1024
#define NIN 4096

typedef __attribute__((ext_vector_type(8))) short bf16x8;
typedef __attribute__((ext_vector_type(4))) short bf16x4;
typedef __attribute__((ext_vector_type(4))) float f32x4;
typedef unsigned long long u64;

#define WM_BYTES (64 * 2048)          /* 64 rows x 1024 bf16, swizzled       */
#define HLDS_OFF WM_BYTES             /* 16 students x 512 bf16 (one K half) */
#define HLDS_BYTES (16 * 1024)
#define HOUT_OFF HLDS_OFF             /* reused after MFMA loop              */
#define LOGIT_OFF (HLDS_OFF + 2048)   /* 4 waves x 16 f32                    */
#define SMEM_BYTES (WM_BYTES + HLDS_BYTES) /* 147456 */

/* workspace layout (bytes) */
#define H0_OFF 0
#define H1_OFF (512 * 1024)
#define LG_OFF (1024 * 1024)            /* logits [100][256] f32 = 100 KB      */
#define BAR_OFF (LG_OFF + 102400)       /* 16 sgs x 128 B, monotonic counters  */

#define AGENT __HIP_MEMORY_SCOPE_AGENT

__device__ inline unsigned short f2bf(float f) {
    union { float f; unsigned int u; } c; c.f = f;
    unsigned int u = c.u + 0x7fffu + ((c.u >> 16) & 1u);
    return (unsigned short)(u >> 16);
}

/* 16-block monotonic barrier: one fetch_add, spin until cnt >= target.
   Each wave drains its vmem before __syncthreads so all h/logit stores are
   at the coherence point before tid0 signals arrival. */
__device__ __forceinline__ void sg_bar(unsigned* cnt, unsigned target) {
    asm volatile("s_waitcnt vmcnt(0)" ::: "memory");
    __syncthreads();
    if (threadIdx.x == 0) {
        __hip_atomic_fetch_add(cnt, 1u, __ATOMIC_RELAXED, AGENT);
        while (__hip_atomic_load(cnt, __ATOMIC_RELAXED, AGENT) < target) {}
    }
    __syncthreads();
}

__global__ void ws_init(float* __restrict__ logits, unsigned* __restrict__ bar) {
    int idx = blockIdx.x * blockDim.x + threadIdx.x;
    if (idx < T_STEPS * B) logits[idx] = 0.f;
    if (idx < 512) bar[idx] = 0u;
}

__global__ __launch_bounds__(256, 1) void rnn_persistent(
    const int* __restrict__ x_idx, const int* __restrict__ y_idx,
    const float* __restrict__ truth,
    const float* __restrict__ Wm, const float* __restrict__ bm,
    const float* __restrict__ Wx, const float* __restrict__ bx_,
    const float* __restrict__ Wy, const float* __restrict__ by,
    const float* __restrict__ b_start,
    __hip_bfloat16* __restrict__ h0buf, __hip_bfloat16* __restrict__ h1buf,
    float* __restrict__ logits, unsigned* __restrict__ bar,
    float* __restrict__ out)
{
    extern __shared__ char lds[];

    const int tid = threadIdx.x;
    const int bid = blockIdx.x;
    const int rg = bid & 15;          /* row group: rows [rg*64, +64)  */
    const int sg = bid >> 4;          /* student group: [sg*16, +16)   */
    const int sbase = sg * 16;
    const int w  = tid >> 6;          /* wave 0..3 -> rows w*16..+15   */
    const int l  = tid & 63;
    const int lr = l & 15;
    const int g  = l >> 4;

    unsigned* bcnt = bar + sg * 32;   /* 128 B apart */

    /* ---- one-time setup ---- */
    /* Wm rows [rg*64,+64) -> LDS bf16, 16B-slot XOR-swizzled by row&7 */
    for (int it = 0; it < 64; ++it) {
        int idx4 = it * 256 + tid;
        int row  = idx4 >> 8;
        int kq   = (idx4 & 255) << 2;
        float4 v = *reinterpret_cast<const float4*>(&Wm[(size_t)(rg * 64 + row) * H + kq]);
        bf16x4 b4;
        b4[0] = (short)f2bf(v.x); b4[1] = (short)f2bf(v.y);
        b4[2] = (short)f2bf(v.z); b4[3] = (short)f2bf(v.w);
        int byte = row * 2048 + (((kq >> 3) ^ (row & 7)) << 4) + ((kq & 7) << 1);
        *reinterpret_cast<bf16x4*>(&lds[byte]) = b4;
    }
    /* h0 = b_start broadcast (zeros @ W_start.T == 0), agent-scope stores */
    {
        int s = tid >> 4, c8 = tid & 15;
        union { unsigned short s4[4]; u64 u; } pk;
        #pragma unroll
        for (int e = 0; e < 4; ++e) pk.s4[e] = f2bf(b_start[rg * 64 + c8 * 4 + e]);
        __hip_atomic_store((u64*)&h0buf[(size_t)(sbase + s) * H + rg * 64 + c8 * 4],
                           pk.u, __ATOMIC_RELAXED, AGENT);
    }
    /* per-lane row-invariant bias */
    float bias_r[4];
    #pragma unroll
    for (int r = 0; r < 4; ++r) {
        int gi = rg * 64 + w * 16 + g * 4 + r;
        bias_r[r] = bm[gi] + bx_[gi];
    }

    sg_bar(bcnt, 16u);

    /* ---- recurrence ---- */
    const int arow = w * 16 + lr;
    for (int t = 0; t < T_STEPS; ++t) {
        const __hip_bfloat16* hc = (t & 1) ? h1buf : h0buf;
        __hip_bfloat16*       hn = (t & 1) ? h0buf : h1buf;

        /* early gathers (read-only data, normal loads) */
        int xc = x_idx[t * B + sbase + lr];
        int yc = y_idx[t * B + sbase + lr];
        float wx_r[4], wy_r[4];
        #pragma unroll
        for (int r = 0; r < 4; ++r) {
            int gi = rg * 64 + w * 16 + g * 4 + r;
            wx_r[r] = Wx[(size_t)gi * NIN + xc];
            wy_r[r] = Wy[(size_t)yc * H + gi];
        }

        /* prefetch both h halves into registers (agent atomic loads, MALL) */
        u64 r0[8], r1[8];
        #pragma unroll
        for (int it = 0; it < 4; ++it) {
            int q = it * 256 + tid;
            int srow = q >> 6, sl = q & 63;
            const u64* src = (const u64*)&hc[(size_t)(sbase + srow) * H + sl * 8];
            r0[2 * it]     = __hip_atomic_load(src,     __ATOMIC_RELAXED, AGENT);
            r0[2 * it + 1] = __hip_atomic_load(src + 1, __ATOMIC_RELAXED, AGENT);
        }
        #pragma unroll
        for (int it = 0; it < 4; ++it) {
            int q = it * 256 + tid;
            int srow = q >> 6, sl = q & 63;
            const u64* src = (const u64*)&hc[(size_t)(sbase + srow) * H + 512 + sl * 8];
            r1[2 * it]     = __hip_atomic_load(src,     __ATOMIC_RELAXED, AGENT);
            r1[2 * it + 1] = __hip_atomic_load(src + 1, __ATOMIC_RELAXED, AGENT);
        }

        f32x4 acc = {0.f, 0.f, 0.f, 0.f};

        /* half 0 */
        #pragma unroll
        for (int it = 0; it < 4; ++it) {
            int q = it * 256 + tid;
            int srow = q >> 6, sl = q & 63;
            union { u64 u[2]; bf16x8 v; } cvt;
            cvt.u[0] = r0[2 * it]; cvt.u[1] = r0[2 * it + 1];
            *reinterpret_cast<bf16x8*>(
                &lds[HLDS_OFF + srow * 1024 + ((sl ^ (srow & 7)) << 4)]) = cvt.v;
        }
        __syncthreads();
        #pragma unroll
        for (int kk = 0; kk < 16; ++kk) {
            int aslot = kk * 4 + g;
            bf16x8 a = *reinterpret_cast<const bf16x8*>(
                &lds[arow * 2048 + ((aslot ^ (arow & 7)) << 4)]);
            bf16x8 bb = *reinterpret_cast<const bf16x8*>(
                &lds[HLDS_OFF + lr * 1024 + (((kk * 4 + g) ^ (lr & 7)) << 4)]);
            acc = __builtin_amdgcn_mfma_f32_16x16x32_bf16(a, bb, acc, 0, 0, 0);
        }
        __syncthreads();
        /* half 1 */
        #pragma unroll
        for (int it = 0; it < 4; ++it) {
            int q = it * 256 + tid;
            int srow = q >> 6, sl = q & 63;
            union { u64 u[2]; bf16x8 v; } cvt;
            cvt.u[0] = r1[2 * it]; cvt.u[1] = r1[2 * it + 1];
            *reinterpret_cast<bf16x8*>(
                &lds[HLDS_OFF + srow * 1024 + ((sl ^ (srow & 7)) << 4)]) = cvt.v;
        }
        __syncthreads();
        #pragma unroll
        for (int kk = 0; kk < 16; ++kk) {
            int aslot = 64 + kk * 4 + g;
            bf16x8 a = *reinterpret_cast<const bf16x8*>(
                &lds[arow * 2048 + ((aslot ^ (arow & 7)) << 4)]);
            bf16x8 bb = *reinterpret_cast<const bf16x8*>(
                &lds[HLDS_OFF + lr * 1024 + (((kk * 4 + g) ^ (lr & 7)) << 4)]);
            acc = __builtin_amdgcn_mfma_f32_16x16x32_bf16(a, bb, acc, 0, 0, 0);
        }
        __syncthreads();

        /* epilogue */
        float hv[4];
        #pragma unroll
        for (int r = 0; r < 4; ++r)
            hv[r] = tanhf(acc[r] + bias_r[r] + wx_r[r]);

        {   /* h_out tile -> LDS (swizzled by student) */
            int row0  = w * 16 + g * 4;
            int chunk = row0 >> 3;
            bf16x4 b4;
            b4[0] = (short)f2bf(hv[0]); b4[1] = (short)f2bf(hv[1]);
            b4[2] = (short)f2bf(hv[2]); b4[3] = (short)f2bf(hv[3]);
            int byte = HOUT_OFF + lr * 128 + ((chunk ^ (lr & 7)) << 4) + ((row0 & 7) << 1);
            *reinterpret_cast<bf16x4*>(&lds[byte]) = b4;
        }
        {   /* logit partial: wave's 16 rows for student lr */
            float p = hv[0] * wy_r[0] + hv[1] * wy_r[1] + hv[2] * wy_r[2] + hv[3] * wy_r[3];
            p += __shfl_down(p, 32);
            p += __shfl_down(p, 16);
            if (l < 16)
                *reinterpret_cast<float*>(&lds[LOGIT_OFF + (w * 16 + l) * 4]) = p;
        }
        __syncthreads();
        {   /* h_next write-out: agent atomic 8B stores */
            int s = tid >> 4, c8 = tid & 15;
            u64 v = *reinterpret_cast<const u64*>(
                &lds[HOUT_OFF + s * 128 + (((c8 >> 1) ^ (s & 7)) << 4) + ((c8 & 1) << 3)]);
            __hip_atomic_store((u64*)&hn[(size_t)(sbase + s) * H + rg * 64 + c8 * 4],
                               v, __ATOMIC_RELAXED, AGENT);
        }
        if (tid < 16) {   /* this block's logit partial for its 16 students */
            const float* lg = reinterpret_cast<const float*>(&lds[LOGIT_OFF]);
            float ps = lg[tid] + lg[16 + tid] + lg[32 + tid] + lg[48 + tid];
            atomicAdd(&logits[t * B + sbase + tid], ps);  /* device-scope */
        }
        sg_bar(bcnt, 16u * (t + 2));
    }

    /* ---- final: block (rg,sg) handles t = rg, rg+16, ... for its 16 students ---- */
    {
        int ti = tid >> 4, s = tid & 15;
        int t = rg + ti * 16;
        if (t < T_STEPS) {
            int idx = t * B + sbase + s;
            float lgv = __hip_atomic_load(&logits[idx], __ATOMIC_RELAXED, AGENT);
            int yc = y_idx[idx];
            lgv += by[yc];
            float pred = 1.f / (1.f + expf(-lgv));
            float tv = truth[idx];
            float e = log1pf(expf(-fabsf(lgv)));
            float ls_pos = fminf(lgv, 0.f) - e;
            float ls_neg = fminf(-lgv, 0.f) - e;
            out[idx] = pred;
            out[T_STEPS * B + idx] = -(tv * ls_pos + (1.f - tv) * ls_neg);
        }
    }
}

extern "C" void kernel_launch(void* const* d_in, const int* in_sizes, int n_in,
                              void* d_out, int out_size, void* d_ws, size_t ws_size,
                              hipStream_t stream) {
    const int*   x_idx   = (const int*)d_in[0];
    const int*   y_idx   = (const int*)d_in[1];
    const float* truth   = (const float*)d_in[2];
    const float* Wm      = (const float*)d_in[3];
    const float* bm      = (const float*)d_in[4];
    const float* Wx      = (const float*)d_in[5];
    const float* bx_     = (const float*)d_in[6];
    const float* Wy      = (const float*)d_in[7];
    const float* by      = (const float*)d_in[8];
    /* d_in[9] = W_start: dead (multiplied by zeros) */
    const float* b_start = (const float*)d_in[10];
    float* out = (float*)d_out;

    __hip_bfloat16* h0buf  = (__hip_bfloat16*)((char*)d_ws + H0_OFF);
    __hip_bfloat16* h1buf  = (__hip_bfloat16*)((char*)d_ws + H1_OFF);
    float*          logits = (float*)((char*)d_ws + LG_OFF);
    unsigned*       bar    = (unsigned*)((char*)d_ws + BAR_OFF);

    ws_init<<<(T_STEPS * B + 255) / 256, 256, 0, stream>>>(logits, bar);

    hipFuncSetAttribute(reinterpret_cast<const void*>(rnn_persistent),
                        hipFuncAttributeMaxDynamicSharedMemorySize, SMEM_BYTES);

    void* args[] = {
        (void*)&x_idx, (void*)&y_idx, (void*)&truth,
        (void*)&Wm, (void*)&bm, (void*)&Wx, (void*)&bx_,
        (void*)&Wy, (void*)&by, (void*)&b_start,
        (void*)&h0buf, (void*)&h1buf, (void*)&logits, (void*)&bar, (void*)&out
    };
    hipLaunchCooperativeKernel(reinterpret_cast<void*>(rnn_persistent),
                               dim3(256), dim3(256), args, SMEM_BYTES, stream);
}

// Round 7
// 466.477 us; speedup vs baseline: 7.4306x; 1.0563x over previous
//
#include <hip/hip_runtime.h>
#include <hip/hip_bf16.h>
#include <math.h>

#define T_STEPS 100
#define B 256
#define Q 2048
#define H 1024
#define NIN 4096

typedef __attribute__((ext_vector_type(8))) short bf16x8;
typedef __attribute__((ext_vector_type(4))) short bf16x4;
typedef __attribute__((ext_vector_type(4))) float f32x4;
typedef unsigned long long u64;

/* dynamic LDS layout (bytes) — no Wm tile (A lives in registers) */
#define HLDS_OFF 0                    /* 16 students x 512 bf16 (one K half), swizzled: 16 KB */
#define HOUT_OFF 16384                /* 16 students x 64 cols bf16: 2 KB */
#define LOGIT_OFF (16384 + 2048)      /* 4 waves x 16 f32: 256 B          */
#define SMEM_BYTES (LOGIT_OFF + 256)  /* 18688 */

/* workspace layout (bytes) */
#define H0_OFF 0
#define H1_OFF (512 * 1024)
#define LG_OFF (1024 * 1024)            /* logits [100][256] f32 = 100 KB      */
#define BAR_OFF (LG_OFF + 102400)       /* 16 sgs x 128 B, monotonic counters  */

#define AGENT __HIP_MEMORY_SCOPE_AGENT

__device__ inline unsigned short f2bf(float f) {
    union { float f; unsigned int u; } c; c.f = f;
    unsigned int u = c.u + 0x7fffu + ((c.u >> 16) & 1u);
    return (unsigned short)(u >> 16);
}

/* 16-block monotonic barrier (round-4 proven): one fetch_add, spin to target.
   vmcnt drain per wave before __syncthreads -> all stores at coherence point
   before tid0 signals arrival. */
__device__ __forceinline__ void sg_bar(unsigned* cnt, unsigned target) {
    asm volatile("s_waitcnt vmcnt(0)" ::: "memory");
    __syncthreads();
    if (threadIdx.x == 0) {
        __hip_atomic_fetch_add(cnt, 1u, __ATOMIC_RELAXED, AGENT);
        while (__hip_atomic_load(cnt, __ATOMIC_RELAXED, AGENT) < target) {}
    }
    __syncthreads();
}

__global__ void ws_init(float* __restrict__ logits, unsigned* __restrict__ bar) {
    int idx = blockIdx.x * blockDim.x + threadIdx.x;
    if (idx < T_STEPS * B) logits[idx] = 0.f;
    if (idx < 512) bar[idx] = 0u;
}

__global__ __launch_bounds__(256, 1) void rnn_persistent(
    const int* __restrict__ x_idx, const int* __restrict__ y_idx,
    const float* __restrict__ truth,
    const float* __restrict__ Wm, const float* __restrict__ bm,
    const float* __restrict__ Wx, const float* __restrict__ bx_,
    const float* __restrict__ Wy, const float* __restrict__ by,
    const float* __restrict__ b_start,
    __hip_bfloat16* __restrict__ h0buf, __hip_bfloat16* __restrict__ h1buf,
    float* __restrict__ logits, unsigned* __restrict__ bar,
    float* __restrict__ out)
{
    extern __shared__ char lds[];

    const int tid = threadIdx.x;
    const int bid = blockIdx.x;
    const int rg = bid & 15;          /* row group: rows [rg*64, +64)  */
    const int sg = bid >> 4;          /* student group: [sg*16, +16)   */
    const int sbase = sg * 16;
    const int w  = tid >> 6;          /* wave 0..3 -> rows w*16..+15   */
    const int l  = tid & 63;
    const int lr = l & 15;
    const int g  = l >> 4;

    unsigned* bcnt = bar + sg * 32;   /* 128 B apart */

    /* ---- one-time setup ---- */
    /* A-fragments for my wave's 16 output rows -> registers (32 x bf16x8).
       Element-identical to round-4's LDS round-trip: row = rg*64+w*16+lr,
       elements [(half*64+kk*4+g)*8, +8), f2bf RNE. */
    bf16x8 a_frag[32];
    {
        const int row = rg * 64 + w * 16 + lr;
        const float* wrow = &Wm[(size_t)row * H];
        #pragma unroll
        for (int half = 0; half < 2; ++half) {
            #pragma unroll
            for (int kk = 0; kk < 16; ++kk) {
                int k0 = (half * 64 + kk * 4 + g) * 8;
                float4 v0 = *reinterpret_cast<const float4*>(&wrow[k0]);
                float4 v1 = *reinterpret_cast<const float4*>(&wrow[k0 + 4]);
                bf16x8 f;
                f[0] = (short)f2bf(v0.x); f[1] = (short)f2bf(v0.y);
                f[2] = (short)f2bf(v0.z); f[3] = (short)f2bf(v0.w);
                f[4] = (short)f2bf(v1.x); f[5] = (short)f2bf(v1.y);
                f[6] = (short)f2bf(v1.z); f[7] = (short)f2bf(v1.w);
                a_frag[half * 16 + kk] = f;
            }
        }
    }
    /* h0 = b_start broadcast (zeros @ W_start.T == 0), agent-scope stores */
    {
        int s = tid >> 4, c8 = tid & 15;
        union { unsigned short s4[4]; u64 u; } pk;
        #pragma unroll
        for (int e = 0; e < 4; ++e) pk.s4[e] = f2bf(b_start[rg * 64 + c8 * 4 + e]);
        __hip_atomic_store((u64*)&h0buf[(size_t)(sbase + s) * H + rg * 64 + c8 * 4],
                           pk.u, __ATOMIC_RELAXED, AGENT);
    }
    /* per-lane row-invariant bias */
    float bias_r[4];
    #pragma unroll
    for (int r = 0; r < 4; ++r) {
        int gi = rg * 64 + w * 16 + g * 4 + r;
        bias_r[r] = bm[gi] + bx_[gi];
    }

    sg_bar(bcnt, 16u);

    /* ---- recurrence ---- */
    for (int t = 0; t < T_STEPS; ++t) {
        const __hip_bfloat16* hc = (t & 1) ? h1buf : h0buf;
        __hip_bfloat16*       hn = (t & 1) ? h0buf : h1buf;

        /* early gathers (read-only data, normal loads) — round-4 placement */
        int xc = x_idx[t * B + sbase + lr];
        int yc = y_idx[t * B + sbase + lr];
        float wx_r[4], wy_r[4];
        #pragma unroll
        for (int r = 0; r < 4; ++r) {
            int gi = rg * 64 + w * 16 + g * 4 + r;
            wx_r[r] = Wx[(size_t)gi * NIN + xc];
            wy_r[r] = Wy[(size_t)yc * H + gi];
        }

        /* prefetch both h halves into registers (agent atomic loads, MALL) */
        u64 r0[8], r1[8];
        #pragma unroll
        for (int it = 0; it < 4; ++it) {
            int q = it * 256 + tid;
            int srow = q >> 6, sl = q & 63;
            const u64* src = (const u64*)&hc[(size_t)(sbase + srow) * H + sl * 8];
            r0[2 * it]     = __hip_atomic_load(src,     __ATOMIC_RELAXED, AGENT);
            r0[2 * it + 1] = __hip_atomic_load(src + 1, __ATOMIC_RELAXED, AGENT);
        }
        #pragma unroll
        for (int it = 0; it < 4; ++it) {
            int q = it * 256 + tid;
            int srow = q >> 6, sl = q & 63;
            const u64* src = (const u64*)&hc[(size_t)(sbase + srow) * H + 512 + sl * 8];
            r1[2 * it]     = __hip_atomic_load(src,     __ATOMIC_RELAXED, AGENT);
            r1[2 * it + 1] = __hip_atomic_load(src + 1, __ATOMIC_RELAXED, AGENT);
        }

        f32x4 acc = {0.f, 0.f, 0.f, 0.f};

        /* half 0 */
        #pragma unroll
        for (int it = 0; it < 4; ++it) {
            int q = it * 256 + tid;
            int srow = q >> 6, sl = q & 63;
            union { u64 u[2]; bf16x8 v; } cvt;
            cvt.u[0] = r0[2 * it]; cvt.u[1] = r0[2 * it + 1];
            *reinterpret_cast<bf16x8*>(
                &lds[HLDS_OFF + srow * 1024 + ((sl ^ (srow & 7)) << 4)]) = cvt.v;
        }
        __syncthreads();
        #pragma unroll
        for (int kk = 0; kk < 16; ++kk) {
            bf16x8 bb = *reinterpret_cast<const bf16x8*>(
                &lds[HLDS_OFF + lr * 1024 + (((kk * 4 + g) ^ (lr & 7)) << 4)]);
            acc = __builtin_amdgcn_mfma_f32_16x16x32_bf16(a_frag[kk], bb, acc, 0, 0, 0);
        }
        __syncthreads();
        /* half 1 */
        #pragma unroll
        for (int it = 0; it < 4; ++it) {
            int q = it * 256 + tid;
            int srow = q >> 6, sl = q & 63;
            union { u64 u[2]; bf16x8 v; } cvt;
            cvt.u[0] = r1[2 * it]; cvt.u[1] = r1[2 * it + 1];
            *reinterpret_cast<bf16x8*>(
                &lds[HLDS_OFF + srow * 1024 + ((sl ^ (srow & 7)) << 4)]) = cvt.v;
        }
        __syncthreads();
        #pragma unroll
        for (int kk = 0; kk < 16; ++kk) {
            bf16x8 bb = *reinterpret_cast<const bf16x8*>(
                &lds[HLDS_OFF + lr * 1024 + (((kk * 4 + g) ^ (lr & 7)) << 4)]);
            acc = __builtin_amdgcn_mfma_f32_16x16x32_bf16(a_frag[16 + kk], bb, acc, 0, 0, 0);
        }
        __syncthreads();

        /* epilogue */
        float hv[4];
        #pragma unroll
        for (int r = 0; r < 4; ++r)
            hv[r] = tanhf(acc[r] + bias_r[r] + wx_r[r]);

        {   /* h_out tile -> LDS (swizzled by student) */
            int row0  = w * 16 + g * 4;
            int chunk = row0 >> 3;
            bf16x4 b4;
            b4[0] = (short)f2bf(hv[0]); b4[1] = (short)f2bf(hv[1]);
            b4[2] = (short)f2bf(hv[2]); b4[3] = (short)f2bf(hv[3]);
            int byte = HOUT_OFF + lr * 128 + ((chunk ^ (lr & 7)) << 4) + ((row0 & 7) << 1);
            *reinterpret_cast<bf16x4*>(&lds[byte]) = b4;
        }
        {   /* logit partial: wave's 16 rows for student lr */
            float p = hv[0] * wy_r[0] + hv[1] * wy_r[1] + hv[2] * wy_r[2] + hv[3] * wy_r[3];
            p += __shfl_down(p, 32);
            p += __shfl_down(p, 16);
            if (l < 16)
                *reinterpret_cast<float*>(&lds[LOGIT_OFF + (w * 16 + l) * 4]) = p;
        }
        __syncthreads();
        {   /* h_next write-out: agent atomic 8B stores */
            int s = tid >> 4, c8 = tid & 15;
            u64 v = *reinterpret_cast<const u64*>(
                &lds[HOUT_OFF + s * 128 + (((c8 >> 1) ^ (s & 7)) << 4) + ((c8 & 1) << 3)]);
            __hip_atomic_store((u64*)&hn[(size_t)(sbase + s) * H + rg * 64 + c8 * 4],
                               v, __ATOMIC_RELAXED, AGENT);
        }
        if (tid < 16) {   /* this block's logit partial for its 16 students */
            const float* lg = reinterpret_cast<const float*>(&lds[LOGIT_OFF]);
            float ps = lg[tid] + lg[16 + tid] + lg[32 + tid] + lg[48 + tid];
            atomicAdd(&logits[t * B + sbase + tid], ps);  /* device-scope */
        }

        sg_bar(bcnt, 16u * (t + 2));
    }

    /* ---- final: block (rg,sg) handles t = rg, rg+16, ... for its 16 students ---- */
    {
        int ti = tid >> 4, s = tid & 15;
        int t = rg + ti * 16;
        if (t < T_STEPS) {
            int idx = t * B + sbase + s;
            float lgv = __hip_atomic_load(&logits[idx], __ATOMIC_RELAXED, AGENT);
            int yc = y_idx[idx];
            lgv += by[yc];
            float pred = 1.f / (1.f + expf(-lgv));
            float tv = truth[idx];
            float e = log1pf(expf(-fabsf(lgv)));
            float ls_pos = fminf(lgv, 0.f) - e;
            float ls_neg = fminf(-lgv, 0.f) - e;
            out[idx] = pred;
            out[T_STEPS * B + idx] = -(tv * ls_pos + (1.f - tv) * ls_neg);
        }
    }
}

extern "C" void kernel_launch(void* const* d_in, const int* in_sizes, int n_in,
                              void* d_out, int out_size, void* d_ws, size_t ws_size,
                              hipStream_t stream) {
    const int*   x_idx   = (const int*)d_in[0];
    const int*   y_idx   = (const int*)d_in[1];
    const float* truth   = (const float*)d_in[2];
    const float* Wm      = (const float*)d_in[3];
    const float* bm      = (const float*)d_in[4];
    const float* Wx      = (const float*)d_in[5];
    const float* bx_     = (const float*)d_in[6];
    const float* Wy      = (const float*)d_in[7];
    const float* by      = (const float*)d_in[8];
    /* d_in[9] = W_start: dead (multiplied by zeros) */
    const float* b_start = (const float*)d_in[10];
    float* out = (float*)d_out;

    __hip_bfloat16* h0buf  = (__hip_bfloat16*)((char*)d_ws + H0_OFF);
    __hip_bfloat16* h1buf  = (__hip_bfloat16*)((char*)d_ws + H1_OFF);
    float*          logits = (float*)((char*)d_ws + LG_OFF);
    unsigned*       bar    = (unsigned*)((char*)d_ws + BAR_OFF);

    ws_init<<<(T_STEPS * B + 255) / 256, 256, 0, stream>>>(logits, bar);

    /* plain launch: 256 blocks on 256 CUs are unconditionally co-resident
       (1 block/CU floor: 18.7 KB LDS, 4 waves, any VGPR count). No
       cooperative-launch validation that can silently reject the kernel. */
    rnn_persistent<<<dim3(256), dim3(256), SMEM_BYTES, stream>>>(
        x_idx, y_idx, truth, Wm, bm, Wx, bx_, Wy, by, b_start,
        h0buf, h1buf, logits, bar, out);
}